// Round 15
// baseline (1039.123 us; speedup 1.0000x reference)
//
#include <hip/hip_runtime.h>
#include <hip/hip_bf16.h>
#include <math.h>

// NTM forward, fully fused: one block per batch element, T=64 steps in-kernel.
// Rev 15 = Rev 13 (measured best: 870us steady / 980 harness) + one additive
// micro-opt. Rev 14's segment merge regressed (900us): 2nd confirmation that
// appending work to a hot wave's pole costs more than a barrier. Revert.
// Delta vs rev 13: the 12 head-scalar activations (2x softplus/sigmoid/3-way
// softmax, ~10 transcendentals) were recomputed redundantly by ALL 512
// threads at the head of SEG4's and SEG6's critical paths. Now wave 4
// (idle in SEG3) computes them once (per-lane, rev-10 pattern, bit-identical
// expressions) into sm.scal[]; SEG4/SEG6 start with 6 LDS broadcasts instead.
// Everything else identical to rev 13: fp32 pack, si-split coalesced GEMVs,
// outc on SEG2 wave 5, hierarchical M (reg row + LDS row), 8 barriers,
// unnormalized-p butterfly.

constexpr int kB  = 64;
constexpr int kT  = 64;
constexpr int kIN = 64;
constexpr int kC  = 256;
constexpr int kN  = 1024;
constexpr int kMV = 64;
constexpr int kOUT = 64;
constexpr int kHW = 198;   // write head raw dim: MV+6+2*MV
constexpr int kHR = 70;    // read head raw dim: MV+6
constexpr int kHO = kHW + kHR;  // 268 head outputs
constexpr int kHCP = 320;  // HeadCat padded output pitch
constexpr int NT  = 512;   // threads per block (8 waves)
constexpr int NW  = NT / 64;
constexpr float kEPS = 1e-8f;

// packed fp32 weight layout, offsets in elements
constexpr int kPWcT = 0;                           // WcT [256][128]
constexpr int kPHc  = kPWcT + kC * 128;            // HeadCat [256][320] @ 32768
constexpr int kPWfT = kPHc + kC * kHCP;            // WfT [64][320]  @ 114688
constexpr int kPWcR = kPWfT + kOUT * (kC + kMV);   // WcR [64][256]  @ 135168
constexpr int kPWfR = kPWcR + kMV * kC;            // WfR [256][64]  @ 151552
constexpr int kPTotal = kPWfR + kC * kOUT;         // 167936 elements
constexpr size_t kWsPack = 256 + (size_t)kPTotal * 4;            // ~656KB
constexpr int kCpreElems = kB * kT * kC;                          // 1M floats
constexpr size_t kWsFull = kWsPack + (size_t)kCpreElems * 4;      // ~4.9MB

__device__ __forceinline__ float ldf(const float* p, int i) { return p[i]; }
__device__ __forceinline__ float ldf(const __hip_bfloat16* p, int i) { return __bfloat162float(p[i]); }
__device__ __forceinline__ void stf(float* p, int i, float v) { p[i] = v; }
__device__ __forceinline__ void stf(__hip_bfloat16* p, int i, float v) { p[i] = __float2bfloat16(v); }

// 8 contiguous elements -> float[8]; 16B-aligned by construction.
__device__ __forceinline__ void ld8(const __hip_bfloat16* p, float* f) {
  uint4 u = *reinterpret_cast<const uint4*>(p);
  f[0] = __uint_as_float(u.x << 16); f[1] = __uint_as_float(u.x & 0xffff0000u);
  f[2] = __uint_as_float(u.y << 16); f[3] = __uint_as_float(u.y & 0xffff0000u);
  f[4] = __uint_as_float(u.z << 16); f[5] = __uint_as_float(u.z & 0xffff0000u);
  f[6] = __uint_as_float(u.w << 16); f[7] = __uint_as_float(u.w & 0xffff0000u);
}
__device__ __forceinline__ void ld8(const float* p, float* f) {
  float4 a = reinterpret_cast<const float4*>(p)[0];
  float4 b = reinterpret_cast<const float4*>(p)[1];
  f[0] = a.x; f[1] = a.y; f[2] = a.z; f[3] = a.w;
  f[4] = b.x; f[5] = b.y; f[6] = b.z; f[7] = b.w;
}

__device__ __forceinline__ float fexp(float v) { return __expf(v); }
__device__ __forceinline__ float sigmoidf_(float v) {
  return __fdividef(1.f, 1.f + __expf(-v));
}
__device__ __forceinline__ float softplusf_(float v) {
  return v > 20.f ? v : __logf(1.f + __expf(v));
}
__device__ __forceinline__ float ftanh(float v) {
  float a = fminf(fabsf(v), 15.f);          // tanh(15) == 1 in fp32
  float e = __expf(2.f * a);
  float t = 1.f - __fdividef(2.f, e + 1.f);
  return v < 0.f ? -t : t;
}

__device__ __forceinline__ float wsum(float v) {
  v += __shfl_xor(v, 32); v += __shfl_xor(v, 16); v += __shfl_xor(v, 8);
  v += __shfl_xor(v, 4);  v += __shfl_xor(v, 2);  v += __shfl_xor(v, 1);
  return v;
}

// 4-accumulator dot of 64 contiguous elements against an LDS vector.
template <typename TD>
__device__ __forceinline__ float dot64(const TD* row, const float* vec) {
  float a0 = 0.f, a1 = 0.f, a2 = 0.f, a3 = 0.f;
  #pragma unroll
  for (int q = 0; q < 8; ++q) {
    float f[8]; ld8(row + 8 * q, f);
    float4 va = *(const float4*)&vec[8 * q];
    float4 vb = *(const float4*)&vec[8 * q + 4];
    a0 = fmaf(va.x, f[0], a0); a1 = fmaf(va.y, f[1], a1);
    a2 = fmaf(va.z, f[2], a2); a3 = fmaf(va.w, f[3], a3);
    a0 = fmaf(vb.x, f[4], a0); a1 = fmaf(vb.y, f[5], a1);
    a2 = fmaf(vb.z, f[6], a2); a3 = fmaf(vb.w, f[7], a3);
  }
  return (a0 + a1) + (a2 + a3);
}

struct alignas(16) Smem {
  // M rows 512..1023: [block b=col/4][row r][4 floats]; lane-contiguous b128.
  float M1s[16 * 512 * 4];   // 128 KB
  float partA[1280];         // [0..268) head dots | [512..576) outc dots
                             // | [768..1280) butterfly wave partials
  float E[kN];               // unnormalized content softmax numerators
  float WP[kN];              // previous weights (for shift conv)
  float c[kC];               // controller activations
  float r[kMV];              // read vector
  float k[kMV], kr[kMV], e[kMV], a[kMV];
  float bcS[kC], bwS[kHW], brS[kHR], bfS[kOUT];   // biases (staged once)
  float red[2][NW];          // cross-wave reduction slots
  float scal[16];            // 0..6 write head (ACTIVATED), 8..14 read head
};
static_assert(sizeof(Smem) <= 160 * 1024, "LDS budget");

__device__ __forceinline__ int m1idx(int blk, int row) { return (blk * 512 + row) * 4; }

// flag: 1 if buffers are bf16, 0 if fp32.  w_bias is a softmax -> sums to 1.
__global__ void detect_dtype(const void* wb, int* flag) {
  const unsigned short* u = (const unsigned short*)wb;
  int lane = threadIdx.x;
  float s = 0.f;
  for (int i = lane; i < kN; i += 64)
    s += __uint_as_float(((unsigned int)u[i]) << 16);
  s = wsum(s);
  if (lane == 0 && blockIdx.x == 0)
    *flag = (s > 0.75f && s < 1.25f) ? 1 : 0;
}

// Repack everything to fp32: WcT, HeadCat, WfT, WcR (rows 64..127), WfR.
template <typename TD, int WANT>
__global__ void repack_w(const TD* __restrict__ Wc, const TD* __restrict__ Ww,
                         const TD* __restrict__ Wr, const TD* __restrict__ Wf,
                         float* __restrict__ pk, const int* __restrict__ flag) {
  if (*flag != WANT) return;
  for (int idx = blockIdx.x * blockDim.x + threadIdx.x; idx < kPTotal;
       idx += gridDim.x * blockDim.x) {
    float v = 0.0f;
    if (idx < kPHc) {                        // WcT[j][i] = Wc[i][j]
      int r = idx, j = r >> 7, i = r & 127;
      v = ldf(Wc, i * kC + j);
    } else if (idx < kPWfT) {                // HeadCat[i][o] = Ww[i][o] || Wr
      int r = idx - kPHc, i = r / kHCP, o = r - i * kHCP;
      if (o < kHW) v = ldf(Ww, i * kHW + o);
      else if (o < kHO) v = ldf(Wr, i * kHR + (o - kHW));
    } else if (idx < kPWcR) {                // WfT[j][i] = Wf[i][j]
      int r = idx - kPWfT, j = r / 320, i = r % 320;
      v = ldf(Wf, i * kOUT + j);
    } else if (idx < kPWfR) {                // WcR[i][j] = Wc[64+i][j]
      int r = idx - kPWcR, i = r >> 8, j = r & 255;
      v = ldf(Wc, (kIN + i) * kC + j);
    } else {                                 // WfR[i][j] = Wf[i][j]
      int r = idx - kPWfR, i = r >> 6, j = r & 63;
      v = ldf(Wf, i * kOUT + j);
    }
    pk[idx] = v;
  }
}

// cpre[b][t][j] = bc[j] + sum_{i<64} x[b][t][i] * Wc[i][j].
template <typename TD, int WANT>
__global__ void cpre_kernel(const TD* __restrict__ x, const TD* __restrict__ bc,
                            const float* __restrict__ pk, float* __restrict__ cpre,
                            const int* __restrict__ flag) {
  if (*flag != WANT) return;
  const int bt = blockIdx.x;              // 0..B*T-1
  const int tid = threadIdx.x;            // output j
  __shared__ float xs[kIN];
  if (tid < kIN) xs[tid] = ldf(x, (size_t)bt * kIN + tid);
  __syncthreads();
  const float* row = pk + kPWcT + tid * 128;  // WcT row j, x-part cols 0..63
  float s = ldf(bc, tid) + dot64(row, xs);
  cpre[(size_t)bt * kC + tid] = s;
}

// MODE: 2 = packed + cpre, 1 = packed (x-part inline), 0 = direct strided.
template <typename TD, int WANT, int MODE>
__global__ __launch_bounds__(NT, 1) void ntm_fused(
    const TD* __restrict__ x,
    const TD* __restrict__ Wc, const TD* __restrict__ bc,
    const TD* __restrict__ Wr, const TD* __restrict__ br,
    const TD* __restrict__ Ww, const TD* __restrict__ bw,
    const TD* __restrict__ Wf, const TD* __restrict__ bf,
    const TD* __restrict__ r_bias, const TD* __restrict__ w_bias,
    const TD* __restrict__ M_bias,
    const float* __restrict__ pk, const float* __restrict__ cpre,
    TD* __restrict__ out, const int* __restrict__ flag) {
  if (*flag != WANT) return;
  __shared__ Smem sm;
  const int tid  = threadIdx.x;
  const int b    = blockIdx.x;
  const int lane = tid & 63;
  const int wid  = tid >> 6;

  // ---- one-time staging: biases, r_bias
  if (tid < kC)  sm.bcS[tid] = ldf(bc, tid);
  if (tid < kHW) sm.bwS[tid] = ldf(bw, tid);
  if (tid < kHR) sm.brS[tid] = ldf(br, tid);
  if (tid < kOUT) sm.bfS[tid] = ldf(bf, tid);
  if (tid < kMV) sm.r[tid] = ldf(r_bias, tid);

  // ---- init state: reg row (tid) + LDS row (tid+512), norms, prev weights
  float M0[kMV];
  float n2_0 = 0.f, n2_1 = 0.f;
  #pragma unroll
  for (int jb = 0; jb < kMV; jb += 8) {
    float f0[8], f1[8];
    ld8(M_bias + (size_t)tid * kMV + jb, f0);
    ld8(M_bias + (size_t)(tid + NT) * kMV + jb, f1);
    #pragma unroll
    for (int u = 0; u < 8; ++u) {
      M0[jb + u] = f0[u];
      n2_0 = fmaf(f0[u], f0[u], n2_0);
      n2_1 = fmaf(f1[u], f1[u], n2_1);
    }
    *(float4*)&sm.M1s[m1idx(jb >> 2, tid)] = make_float4(f1[0], f1[1], f1[2], f1[3]);
    *(float4*)&sm.M1s[m1idx((jb >> 2) + 1, tid)] = make_float4(f1[4], f1[5], f1[6], f1[7]);
  }
  float wp0 = ldf(w_bias, tid);
  float wp1 = ldf(w_bias, tid + NT);
  __syncthreads();

  #pragma unroll 1
  for (int t = 0; t < kT; ++t) {
    // ==== SEG 1: controller (coalesced si-split, waves 0..3)  ||  out store
    //     for step t-1 (threads 256..319).  Both depend only on r_{t-1}.
    if constexpr (MODE == 2) {
      if (tid < 256) {
        const int si = lane >> 3;                 // i-slice 0..7
        const int g  = (wid << 3) + (lane & 7);   // output group 0..31
        const int obase = g * 8;
        float acc[8] = {0.f, 0.f, 0.f, 0.f, 0.f, 0.f, 0.f, 0.f};
        #pragma unroll
        for (int q = 0; q < 8; ++q) {
          int i = (q << 3) + si;
          float rv = sm.r[i];
          float f[8]; ld8(pk + kPWcR + i * kC + obase, f);   // fp32 WcR row
          #pragma unroll
          for (int v = 0; v < 8; ++v) acc[v] = fmaf(rv, f[v], acc[v]);
        }
        #pragma unroll
        for (int v = 0; v < 8; ++v) {
          acc[v] += __shfl_xor(acc[v], 8);
          acc[v] += __shfl_xor(acc[v], 16);
          acc[v] += __shfl_xor(acc[v], 32);
        }
        if (si == 0) {
          const float* cp = &cpre[((size_t)b * kT + t) * kC + obase];
          float4 ca = *(const float4*)cp;
          float4 cb = *(const float4*)(cp + 4);
          sm.c[obase + 0] = ftanh(ca.x + acc[0]);
          sm.c[obase + 1] = ftanh(ca.y + acc[1]);
          sm.c[obase + 2] = ftanh(ca.z + acc[2]);
          sm.c[obase + 3] = ftanh(ca.w + acc[3]);
          sm.c[obase + 4] = ftanh(cb.x + acc[4]);
          sm.c[obase + 5] = ftanh(cb.y + acc[5]);
          sm.c[obase + 6] = ftanh(cb.z + acc[6]);
          sm.c[obase + 7] = ftanh(cb.w + acc[7]);
        }
      } else if (tid < 320 && t > 0) {
        const int j = tid - 256;
        float s = sm.bfS[j] + sm.partA[512 + j];
        s += dot64(pk + kPWfT + j * (kC + kMV) + kC, sm.r);
        stf(out, ((size_t)b * kT + (t - 1)) * kOUT + j, sigmoidf_(s));
      }
    } else {
      if (tid < kC) {
        float s;
        if constexpr (MODE == 1) {
          s = sm.bcS[tid];
          const TD* xrow = x + ((size_t)b * kT + t) * kIN;
          const float* row = pk + kPWcT + tid * 128;
          #pragma unroll
          for (int q = 0; q < 8; ++q) {
            float f[8], xv[8];
            ld8(row + 8 * q, f); ld8(xrow + 8 * q, xv);
            #pragma unroll
            for (int u = 0; u < 8; ++u) s = fmaf(xv[u], f[u], s);
          }
          s += dot64(pk + kPWcT + tid * 128 + 64, sm.r);
        } else {
          s = sm.bcS[tid];
          for (int i = 0; i < kIN; ++i)
            s = fmaf(ldf(x, ((size_t)b * kT + t) * kIN + i), ldf(Wc, i * kC + tid), s);
          for (int i = 0; i < kMV; ++i)
            s = fmaf(sm.r[i], ldf(Wc, (kIN + i) * kC + tid), s);
        }
        sm.c[tid] = ftanh(s);
      } else if (tid < 320 && t > 0) {
        const int j = tid - 256;
        float s = sm.bfS[j] + sm.partA[512 + j];
        if constexpr (MODE == 1) {
          s += dot64(pk + kPWfT + j * (kC + kMV) + kC, sm.r);
        } else {
          for (int i = 0; i < kMV; ++i)
            s = fmaf(sm.r[i], ldf(Wf, (kC + i) * kOUT + j), s);
        }
        stf(out, ((size_t)b * kT + (t - 1)) * kOUT + j, sigmoidf_(s));
      }
    }
    __syncthreads();                                               // B1

    // ==== SEG 2: head full-dots (si-split over HeadCat, waves 0..4)
    //     || outc full-dots (wave 5, si-split over WfR) || waves 6-7 idle
    if constexpr (MODE >= 1) {
      if (wid < 5) {
        const int si = lane >> 3;                 // i-slice 0..7
        const int g  = (wid << 3) + (lane & 7);   // output group 0..39
        const int obase = g * 8;                  // 0..312 (padded rows safe)
        float acc[8] = {0.f, 0.f, 0.f, 0.f, 0.f, 0.f, 0.f, 0.f};
        #pragma unroll 4
        for (int q = 0; q < 32; ++q) {
          int i = (q << 3) + si;
          float cv = sm.c[i];
          float f[8]; ld8(pk + kPHc + i * kHCP + obase, f);
          #pragma unroll
          for (int v = 0; v < 8; ++v) acc[v] = fmaf(cv, f[v], acc[v]);
        }
        #pragma unroll
        for (int v = 0; v < 8; ++v) {
          acc[v] += __shfl_xor(acc[v], 8);
          acc[v] += __shfl_xor(acc[v], 16);
          acc[v] += __shfl_xor(acc[v], 32);
        }
        if (si == 0 && obase < kHO) {
          #pragma unroll
          for (int v = 0; v < 8; ++v)
            if (obase + v < kHO) sm.partA[obase + v] = acc[v];
        }
      } else if (wid == 5) {
        const int si = lane >> 3;
        const int g  = lane & 7;                  // output group 0..7
        const int obase = g * 8;
        float acc[8] = {0.f, 0.f, 0.f, 0.f, 0.f, 0.f, 0.f, 0.f};
        #pragma unroll 4
        for (int q = 0; q < 32; ++q) {
          int i = (q << 3) + si;
          float cv = sm.c[i];
          float f[8]; ld8(pk + kPWfR + i * kOUT + obase, f);
          #pragma unroll
          for (int v = 0; v < 8; ++v) acc[v] = fmaf(cv, f[v], acc[v]);
        }
        #pragma unroll
        for (int v = 0; v < 8; ++v) {
          acc[v] += __shfl_xor(acc[v], 8);
          acc[v] += __shfl_xor(acc[v], 16);
          acc[v] += __shfl_xor(acc[v], 32);
        }
        if (si == 0) {
          *(float4*)&sm.partA[512 + obase] =
              make_float4(acc[0], acc[1], acc[2], acc[3]);
          *(float4*)&sm.partA[512 + obase + 4] =
              make_float4(acc[4], acc[5], acc[6], acc[7]);
        }
      }
    } else {
      if (tid < kHO) {
        float a0 = 0.f;
        for (int i = 0; i < kC; ++i) {
          float wv = (tid < kHW) ? ldf(Ww, i * kHW + tid)
                                 : ldf(Wr, i * kHR + (tid - kHW));
          a0 = fmaf(sm.c[i], wv, a0);
        }
        sm.partA[tid] = a0;
      } else if (wid == 5) {                // outc (strided fallback)
        const int si = lane >> 3;
        const int g  = lane & 7;
        const int obase = g * 8;
        float acc[8] = {0.f, 0.f, 0.f, 0.f, 0.f, 0.f, 0.f, 0.f};
        for (int q = 0; q < 32; ++q) {
          int i = (q << 3) + si;
          float cv = sm.c[i];
          #pragma unroll
          for (int v = 0; v < 8; ++v)
            acc[v] = fmaf(cv, ldf(Wf, i * kOUT + obase + v), acc[v]);
        }
        #pragma unroll
        for (int v = 0; v < 8; ++v) {
          acc[v] += __shfl_xor(acc[v], 8);
          acc[v] += __shfl_xor(acc[v], 16);
          acc[v] += __shfl_xor(acc[v], 32);
        }
        if (si == 0) {
          #pragma unroll
          for (int v = 0; v < 8; ++v) sm.partA[512 + obase + v] = acc[v];
        }
      }
    }
    __syncthreads();                                               // B2

    // ==== SEG 3: head vector params (waves 0..3) || SCALAR ACTIVATIONS
    //     (wave 4, lanes 0..11; previously recomputed by all 512 threads)
    if (wid == 0) {                       // write key + |k|
      float kv = ftanh(sm.partA[lane] + sm.bwS[lane]);
      sm.k[lane] = kv;
      float s = wsum(kv * kv);
      if (lane == 0) sm.scal[6] = sqrtf(s);
    } else if (wid == 1) {                // erase
      sm.e[lane] = sigmoidf_(sm.partA[70 + lane] + sm.bwS[70 + lane]);
    } else if (wid == 2) {                // add
      sm.a[lane] = ftanh(sm.partA[134 + lane] + sm.bwS[134 + lane]);
    } else if (wid == 3) {                // read key + |k|
      float kv = ftanh(sm.partA[kHW + lane] + sm.brS[lane]);
      sm.kr[lane] = kv;
      float s = wsum(kv * kv);
      if (lane == 0) sm.scal[14] = sqrtf(s);
    } else if (wid == 4) {                // 12 head scalars, activated once
      float dot = 0.f;
      if (lane < 6) dot = sm.partA[64 + lane] + sm.bwS[64 + lane];
      else if (lane < 12) dot = sm.partA[kHW + 64 + (lane - 6)] + sm.brS[64 + (lane - 6)];
      float d2 = __shfl(dot, 2), d3 = __shfl(dot, 3), d4 = __shfl(dot, 4);
      float d8 = __shfl(dot, 8), d9 = __shfl(dot, 9), d10 = __shfl(dot, 10);
      if (lane == 0) sm.scal[0] = softplusf_(dot);            // beta_w
      else if (lane == 1) sm.scal[1] = sigmoidf_(dot);        // g_w
      else if (lane == 5) sm.scal[2] = 1.f + softplusf_(dot); // gamma_w
      else if (lane == 2) {                                   // s_w softmax
        float mx = fmaxf(d2, fmaxf(d3, d4));
        float e0 = fexp(d2 - mx), e1 = fexp(d3 - mx), e2 = fexp(d4 - mx);
        float dd = __fdividef(1.f, e0 + e1 + e2);
        sm.scal[3] = e0 * dd; sm.scal[4] = e1 * dd; sm.scal[5] = e2 * dd;
      } else if (lane == 6) sm.scal[8] = softplusf_(dot);     // beta_r
      else if (lane == 7) sm.scal[9] = sigmoidf_(dot);        // g_r
      else if (lane == 11) sm.scal[10] = 1.f + softplusf_(dot); // gamma_r
      else if (lane == 8) {                                   // s_r softmax
        float mx = fmaxf(d8, fmaxf(d9, d10));
        float e0 = fexp(d8 - mx), e1 = fexp(d9 - mx), e2 = fexp(d10 - mx);
        float dd = __fdividef(1.f, e0 + e1 + e2);
        sm.scal[11] = e0 * dd; sm.scal[12] = e1 * dd; sm.scal[13] = e2 * dd;
      }
    }
    __syncthreads();                                               // B3

    // ==== SEG 4: write-head addressing, part 1 (dots + exp + block sum)
    float ww0, ww1, gW, s0W, s1W, s2W, gammaW;
    float e0W, e1W, p0W, p1W;
    {
      float beta = sm.scal[0];
      gW = sm.scal[1];
      gammaW = sm.scal[2];
      s0W = sm.scal[3]; s1W = sm.scal[4]; s2W = sm.scal[5];
      float kn = sm.scal[6];
      float d0a = 0.f, d0b = 0.f, d1a = 0.f, d1b = 0.f;
      #pragma unroll
      for (int bq = 0; bq < 16; ++bq) {
        float4 kv = *(const float4*)&sm.k[bq * 4];
        d0a = fmaf(M0[bq * 4],     kv.x, d0a);
        d0b = fmaf(M0[bq * 4 + 1], kv.y, d0b);
        d0a = fmaf(M0[bq * 4 + 2], kv.z, d0a);
        d0b = fmaf(M0[bq * 4 + 3], kv.w, d0b);
        float4 mv = *(const float4*)&sm.M1s[m1idx(bq, tid)];
        d1a = fmaf(mv.x, kv.x, d1a); d1b = fmaf(mv.y, kv.y, d1b);
        d1a = fmaf(mv.z, kv.z, d1a); d1b = fmaf(mv.w, kv.w, d1b);
      }
      float d0 = d0a + d0b, d1 = d1a + d1b;
      float sim0 = fminf(beta * d0 / (sqrtf(n2_0) * kn + kEPS), 80.f);
      float sim1 = fminf(beta * d1 / (sqrtf(n2_1) * kn + kEPS), 80.f);
      e0W = fexp(sim0); e1W = fexp(sim1);
      sm.E[tid] = e0W; sm.E[tid + NT] = e1W;
      sm.WP[tid] = wp0; sm.WP[tid + NT] = wp1;
      float sv = wsum(e0W + e1W);
      if (lane == 0) sm.red[0][wid] = sv;
    }
    __syncthreads();                                               // B4

    // ==== SEG 5: write-head addressing, part 2 (norm + shift + sharpen)
    {
      float gsum = 0.f;
      #pragma unroll
      for (int i = 0; i < NW; ++i) gsum += sm.red[0][i];
      float inv = __fdividef(1.f, gsum);
      float wg0 = fmaf(gW, fmaf(e0W, inv, -wp0), wp0);
      float wg1 = fmaf(gW, fmaf(e1W, inv, -wp1), wp1);
      int np = (tid + 1) & (kN - 1), nm = (tid + kN - 1) & (kN - 1);
      float wgp = fmaf(gW, fmaf(sm.E[np], inv, -sm.WP[np]), sm.WP[np]);
      float wgm = fmaf(gW, fmaf(sm.E[nm], inv, -sm.WP[nm]), sm.WP[nm]);
      float ws0 = s0W * wgp + s1W * wg0 + s2W * wgm;
      int npb = (tid + NT + 1) & (kN - 1), nmb = (tid + NT - 1) & (kN - 1);
      float wgpb = fmaf(gW, fmaf(sm.E[npb], inv, -sm.WP[npb]), sm.WP[npb]);
      float wgmb = fmaf(gW, fmaf(sm.E[nmb], inv, -sm.WP[nmb]), sm.WP[nmb]);
      float ws1 = s0W * wgpb + s1W * wg1 + s2W * wgmb;
      p0W = fexp(gammaW * __logf(ws0 + kEPS));
      p1W = fexp(gammaW * __logf(ws1 + kEPS));
      float pv = wsum(p0W + p1W);
      if (lane == 0) sm.red[1][wid] = pv;
    }
    __syncthreads();                                               // B5
    {
      float psum = 0.f;
      #pragma unroll
      for (int i = 0; i < NW; ++i) psum += sm.red[1][i];
      float ipn = __fdividef(1.f, psum);
      ww0 = p0W * ipn; ww1 = p1W * ipn;
    }

    // ==== SEG 6: memory update (+ read dot + norms) + read-head part 1
    float gR, s0R, s1R, s2R, gammaR;
    float e0R, e1R, p0R, p1R;
    float dr0 = 0.f, dr1 = 0.f, nn0 = 0.f, nn1 = 0.f;
    {
      #pragma unroll
      for (int bq = 0; bq < 16; ++bq) {
        float4 ev = *(const float4*)&sm.e[bq * 4];
        float4 av = *(const float4*)&sm.a[bq * 4];
        float4 kv = *(const float4*)&sm.kr[bq * 4];
        {
          float m = fmaf(ww0, fmaf(-ev.x, M0[bq * 4], av.x), M0[bq * 4]);
          M0[bq * 4] = m; dr0 = fmaf(m, kv.x, dr0); nn0 = fmaf(m, m, nn0);
        }
        {
          float m = fmaf(ww0, fmaf(-ev.y, M0[bq * 4 + 1], av.y), M0[bq * 4 + 1]);
          M0[bq * 4 + 1] = m; dr0 = fmaf(m, kv.y, dr0); nn0 = fmaf(m, m, nn0);
        }
        {
          float m = fmaf(ww0, fmaf(-ev.z, M0[bq * 4 + 2], av.z), M0[bq * 4 + 2]);
          M0[bq * 4 + 2] = m; dr0 = fmaf(m, kv.z, dr0); nn0 = fmaf(m, m, nn0);
        }
        {
          float m = fmaf(ww0, fmaf(-ev.w, M0[bq * 4 + 3], av.w), M0[bq * 4 + 3]);
          M0[bq * 4 + 3] = m; dr0 = fmaf(m, kv.w, dr0); nn0 = fmaf(m, m, nn0);
        }
        int fi = m1idx(bq, tid);
        float4 mv = *(const float4*)&sm.M1s[fi];
        float4 nm;
        nm.x = fmaf(ww1, fmaf(-ev.x, mv.x, av.x), mv.x);
        dr1 = fmaf(nm.x, kv.x, dr1); nn1 = fmaf(nm.x, nm.x, nn1);
        nm.y = fmaf(ww1, fmaf(-ev.y, mv.y, av.y), mv.y);
        dr1 = fmaf(nm.y, kv.y, dr1); nn1 = fmaf(nm.y, nm.y, nn1);
        nm.z = fmaf(ww1, fmaf(-ev.z, mv.z, av.z), mv.z);
        dr1 = fmaf(nm.z, kv.z, dr1); nn1 = fmaf(nm.z, nm.z, nn1);
        nm.w = fmaf(ww1, fmaf(-ev.w, mv.w, av.w), mv.w);
        dr1 = fmaf(nm.w, kv.w, dr1); nn1 = fmaf(nm.w, nm.w, nn1);
        *(float4*)&sm.M1s[fi] = nm;
      }
      float beta = sm.scal[8];
      gR = sm.scal[9]; gammaR = sm.scal[10];
      s0R = sm.scal[11]; s1R = sm.scal[12]; s2R = sm.scal[13];
      float kn = sm.scal[14];
      float sim0 = fminf(beta * dr0 / (sqrtf(nn0) * kn + kEPS), 80.f);
      float sim1 = fminf(beta * dr1 / (sqrtf(nn1) * kn + kEPS), 80.f);
      e0R = fexp(sim0); e1R = fexp(sim1);
      sm.E[tid] = e0R; sm.E[tid + NT] = e1R;
      sm.WP[tid] = ww0; sm.WP[tid + NT] = ww1;
      float sv = wsum(e0R + e1R);
      if (lane == 0) sm.red[0][wid] = sv;
    }
    __syncthreads();                                               // B6

    // ==== SEG 7: read-head part 2 + butterfly on UNNORMALIZED p
    {
      float gsum = 0.f;
      #pragma unroll
      for (int i = 0; i < NW; ++i) gsum += sm.red[0][i];
      float inv = __fdividef(1.f, gsum);
      float wg0 = fmaf(gR, fmaf(e0R, inv, -ww0), ww0);
      float wg1 = fmaf(gR, fmaf(e1R, inv, -ww1), ww1);
      int np = (tid + 1) & (kN - 1), nm = (tid + kN - 1) & (kN - 1);
      float wgp = fmaf(gR, fmaf(sm.E[np], inv, -sm.WP[np]), sm.WP[np]);
      float wgm = fmaf(gR, fmaf(sm.E[nm], inv, -sm.WP[nm]), sm.WP[nm]);
      float ws0 = s0R * wgp + s1R * wg0 + s2R * wgm;
      int npb = (tid + NT + 1) & (kN - 1), nmb = (tid + NT - 1) & (kN - 1);
      float wgpb = fmaf(gR, fmaf(sm.E[npb], inv, -sm.WP[npb]), sm.WP[npb]);
      float wgmb = fmaf(gR, fmaf(sm.E[nmb], inv, -sm.WP[nmb]), sm.WP[nmb]);
      float ws1 = s0R * wgpb + s1R * wg1 + s2R * wgmb;
      p0R = fexp(gammaR * __logf(ws0 + kEPS));
      p1R = fexp(gammaR * __logf(ws1 + kEPS));
      float pv = wsum(p0R + p1R);
      if (lane == 0) sm.red[1][wid] = pv;
      // butterfly pass A: columns 0..31, weights p0R/p1R (unnormalized)
      {
        float cur[16];
        const int b0 = lane & 1;
        #pragma unroll
        for (int qq = 0; qq < 8; ++qq) {
          float4 mv = *(const float4*)&sm.M1s[m1idx(qq, tid)];
          float v0 = fmaf(p0R, M0[4 * qq],     p1R * mv.x);
          float v1 = fmaf(p0R, M0[4 * qq + 1], p1R * mv.y);
          float keep = b0 ? v1 : v0, send = b0 ? v0 : v1;
          cur[2 * qq] = keep + __shfl_xor(send, 1);
          float v2 = fmaf(p0R, M0[4 * qq + 2], p1R * mv.z);
          float v3 = fmaf(p0R, M0[4 * qq + 3], p1R * mv.w);
          keep = b0 ? v3 : v2; send = b0 ? v2 : v3;
          cur[2 * qq + 1] = keep + __shfl_xor(send, 1);
        }
        #pragma unroll
        for (int st = 1; st < 5; ++st) {
          const int d = 1 << st;
          const int bb = (lane >> st) & 1;
          #pragma unroll
          for (int q = 0; q < (16 >> st); ++q) {
            float x0 = cur[2 * q], x1 = cur[2 * q + 1];
            float keep = bb ? x1 : x0, send = bb ? x0 : x1;
            cur[q] = keep + __shfl_xor(send, d);
          }
        }
        float tot = cur[0] + __shfl_xor(cur[0], 32);
        if (lane < 32) sm.partA[768 + wid * 64 + lane] = tot;
      }
      // butterfly pass B: columns 32..63
      {
        float cur[16];
        const int b0 = lane & 1;
        #pragma unroll
        for (int qq = 0; qq < 8; ++qq) {
          float4 mv = *(const float4*)&sm.M1s[m1idx(8 + qq, tid)];
          float v0 = fmaf(p0R, M0[32 + 4 * qq],     p1R * mv.x);
          float v1 = fmaf(p0R, M0[32 + 4 * qq + 1], p1R * mv.y);
          float keep = b0 ? v1 : v0, send = b0 ? v0 : v1;
          cur[2 * qq] = keep + __shfl_xor(send, 1);
          float v2 = fmaf(p0R, M0[32 + 4 * qq + 2], p1R * mv.z);
          float v3 = fmaf(p0R, M0[32 + 4 * qq + 3], p1R * mv.w);
          keep = b0 ? v3 : v2; send = b0 ? v2 : v3;
          cur[2 * qq + 1] = keep + __shfl_xor(send, 1);
        }
        #pragma unroll
        for (int st = 1; st < 5; ++st) {
          const int d = 1 << st;
          const int bb = (lane >> st) & 1;
          #pragma unroll
          for (int q = 0; q < (16 >> st); ++q) {
            float x0 = cur[2 * q], x1 = cur[2 * q + 1];
            float keep = bb ? x1 : x0, send = bb ? x0 : x1;
            cur[q] = keep + __shfl_xor(send, d);
          }
        }
        float tot = cur[0] + __shfl_xor(cur[0], 32);
        if (lane < 32) sm.partA[768 + wid * 64 + 32 + lane] = tot;
      }
    }
    __syncthreads();                                               // B7

    // ==== SEG 8: psum -> ipn; carry state; r reduce with ipn scaling
    {
      float psum = 0.f;
      #pragma unroll
      for (int i = 0; i < NW; ++i) psum += sm.red[1][i];
      float ipn = __fdividef(1.f, psum);
      wp0 = p0R * ipn; wp1 = p1R * ipn;      // carry normalized read weights
      n2_0 = nn0; n2_1 = nn1;
      if (tid < kMV) {
        float s = sm.partA[768 + tid];
        #pragma unroll
        for (int w = 1; w < NW; ++w) s += sm.partA[768 + w * 64 + tid];
        sm.r[tid] = s * ipn;
      }
    }
    __syncthreads();                                               // B8
  }

  // ==== epilogue: output for t = kT-1 (outc dots + r are intact)
  if (tid >= 256 && tid < 320) {
    const int j = tid - 256;
    float s = sm.bfS[j] + sm.partA[512 + j];
    if constexpr (MODE >= 1) {
      s += dot64(pk + kPWfT + j * (kC + kMV) + kC, sm.r);
    } else {
      for (int i = 0; i < kMV; ++i)
        s = fmaf(sm.r[i], ldf(Wf, (kC + i) * kOUT + j), s);
    }
    stf(out, ((size_t)b * kT + (kT - 1)) * kOUT + j, sigmoidf_(s));
  }
}

template <typename TD, int WANT, int MODE>
static void launch_variant(void* const* d_in, void* d_out, const int* flag,
                           const float* pk, const float* cpre, hipStream_t stream) {
  ntm_fused<TD, WANT, MODE><<<dim3(kB), dim3(NT), 0, stream>>>(
      (const TD*)d_in[0], (const TD*)d_in[1], (const TD*)d_in[2],
      (const TD*)d_in[3], (const TD*)d_in[4], (const TD*)d_in[5],
      (const TD*)d_in[6], (const TD*)d_in[7], (const TD*)d_in[8],
      (const TD*)d_in[9], (const TD*)d_in[10], (const TD*)d_in[11],
      pk, cpre, (TD*)d_out, flag);
}

extern "C" void kernel_launch(void* const* d_in, const int* in_sizes, int n_in,
                              void* d_out, int out_size, void* d_ws, size_t ws_size,
                              hipStream_t stream) {
  (void)in_sizes; (void)n_in; (void)out_size;
  int* flag = (int*)d_ws;
  detect_dtype<<<dim3(1), dim3(64), 0, stream>>>(d_in[10], flag);
  if (ws_size >= kWsPack) {
    float* pk = (float*)((char*)d_ws + 256);
    repack_w<__hip_bfloat16, 1><<<dim3(256), dim3(256), 0, stream>>>(
        (const __hip_bfloat16*)d_in[1], (const __hip_bfloat16*)d_in[5],
        (const __hip_bfloat16*)d_in[3], (const __hip_bfloat16*)d_in[7],
        pk, flag);
    repack_w<float, 0><<<dim3(256), dim3(256), 0, stream>>>(
        (const float*)d_in[1], (const float*)d_in[5],
        (const float*)d_in[3], (const float*)d_in[7],
        pk, flag);
    if (ws_size >= kWsFull) {
      float* cpre = (float*)((char*)d_ws + kWsPack);
      cpre_kernel<__hip_bfloat16, 1><<<dim3(kB * kT), dim3(kC), 0, stream>>>(
          (const __hip_bfloat16*)d_in[0], (const __hip_bfloat16*)d_in[2],
          pk, cpre, flag);
      cpre_kernel<float, 0><<<dim3(kB * kT), dim3(kC), 0, stream>>>(
          (const float*)d_in[0], (const float*)d_in[2],
          pk, cpre, flag);
      launch_variant<__hip_bfloat16, 1, 2>(d_in, d_out, flag, pk, cpre, stream);
      launch_variant<float, 0, 2>(d_in, d_out, flag, pk, cpre, stream);
    } else {
      launch_variant<__hip_bfloat16, 1, 1>(d_in, d_out, flag, pk, nullptr, stream);
      launch_variant<float, 0, 1>(d_in, d_out, flag, pk, nullptr, stream);
    }
  } else {
    launch_variant<__hip_bfloat16, 1, 0>(d_in, d_out, flag, nullptr, nullptr, stream);
    launch_variant<float, 0, 0>(d_in, d_out, flag, nullptr, nullptr, stream);
  }
}

// Round 16
// 953.628 us; speedup vs baseline: 1.0897x; 1.0897x over previous
//
#include <hip/hip_runtime.h>
#include <hip/hip_bf16.h>
#include <math.h>

// NTM forward, fully fused: one block per batch element, T=64 steps in-kernel.
// Rev 16 = Rev 13's main kernel VERBATIM (measured champion: 870us steady /
// 980 harness; revs 14+15 perturbations both regressed 3-7% -- the 8-barrier
// structure is a local optimum) + launch-sequence consolidation:
//   repack + cpre merged into one pre_kernel per dtype (blocks <256 repack,
//   blocks >=256 cpre reading ORIGINAL Wc with the identical acc[i&3]
//   summation order -> bit-identical cpre). 7 launches -> 5.
// Main-kernel history: 2872 (start) -> 1466 (barrier diet) -> 1270 (9-seg
// skeleton + cpre) -> 908 (coalesced si-split GEMVs) -> 870 (fp32 pack +
// outc overlap). Structure is latency-bound on 8 true-dependency barriers
// x 64 steps; HW counters far from any memory/compute roofline.

constexpr int kB  = 64;
constexpr int kT  = 64;
constexpr int kIN = 64;
constexpr int kC  = 256;
constexpr int kN  = 1024;
constexpr int kMV = 64;
constexpr int kOUT = 64;
constexpr int kHW = 198;   // write head raw dim: MV+6+2*MV
constexpr int kHR = 70;    // read head raw dim: MV+6
constexpr int kHO = kHW + kHR;  // 268 head outputs
constexpr int kHCP = 320;  // HeadCat padded output pitch
constexpr int NT  = 512;   // threads per block (8 waves)
constexpr int NW  = NT / 64;
constexpr float kEPS = 1e-8f;

// packed fp32 weight layout, offsets in elements
constexpr int kPWcT = 0;                           // WcT [256][128]
constexpr int kPHc  = kPWcT + kC * 128;            // HeadCat [256][320] @ 32768
constexpr int kPWfT = kPHc + kC * kHCP;            // WfT [64][320]  @ 114688
constexpr int kPWcR = kPWfT + kOUT * (kC + kMV);   // WcR [64][256]  @ 135168
constexpr int kPWfR = kPWcR + kMV * kC;            // WfR [256][64]  @ 151552
constexpr int kPTotal = kPWfR + kC * kOUT;         // 167936 elements
constexpr size_t kWsPack = 256 + (size_t)kPTotal * 4;            // ~656KB
constexpr int kCpreElems = kB * kT * kC;                          // 1M floats
constexpr size_t kWsFull = kWsPack + (size_t)kCpreElems * 4;      // ~4.9MB

__device__ __forceinline__ float ldf(const float* p, int i) { return p[i]; }
__device__ __forceinline__ float ldf(const __hip_bfloat16* p, int i) { return __bfloat162float(p[i]); }
__device__ __forceinline__ void stf(float* p, int i, float v) { p[i] = v; }
__device__ __forceinline__ void stf(__hip_bfloat16* p, int i, float v) { p[i] = __float2bfloat16(v); }

// 8 contiguous elements -> float[8]; 16B-aligned by construction.
__device__ __forceinline__ void ld8(const __hip_bfloat16* p, float* f) {
  uint4 u = *reinterpret_cast<const uint4*>(p);
  f[0] = __uint_as_float(u.x << 16); f[1] = __uint_as_float(u.x & 0xffff0000u);
  f[2] = __uint_as_float(u.y << 16); f[3] = __uint_as_float(u.y & 0xffff0000u);
  f[4] = __uint_as_float(u.z << 16); f[5] = __uint_as_float(u.z & 0xffff0000u);
  f[6] = __uint_as_float(u.w << 16); f[7] = __uint_as_float(u.w & 0xffff0000u);
}
__device__ __forceinline__ void ld8(const float* p, float* f) {
  float4 a = reinterpret_cast<const float4*>(p)[0];
  float4 b = reinterpret_cast<const float4*>(p)[1];
  f[0] = a.x; f[1] = a.y; f[2] = a.z; f[3] = a.w;
  f[4] = b.x; f[5] = b.y; f[6] = b.z; f[7] = b.w;
}

__device__ __forceinline__ float fexp(float v) { return __expf(v); }
__device__ __forceinline__ float sigmoidf_(float v) {
  return __fdividef(1.f, 1.f + __expf(-v));
}
__device__ __forceinline__ float softplusf_(float v) {
  return v > 20.f ? v : __logf(1.f + __expf(v));
}
__device__ __forceinline__ float ftanh(float v) {
  float a = fminf(fabsf(v), 15.f);          // tanh(15) == 1 in fp32
  float e = __expf(2.f * a);
  float t = 1.f - __fdividef(2.f, e + 1.f);
  return v < 0.f ? -t : t;
}

__device__ __forceinline__ float wsum(float v) {
  v += __shfl_xor(v, 32); v += __shfl_xor(v, 16); v += __shfl_xor(v, 8);
  v += __shfl_xor(v, 4);  v += __shfl_xor(v, 2);  v += __shfl_xor(v, 1);
  return v;
}

// 4-accumulator dot of 64 contiguous elements against an LDS vector.
template <typename TD>
__device__ __forceinline__ float dot64(const TD* row, const float* vec) {
  float a0 = 0.f, a1 = 0.f, a2 = 0.f, a3 = 0.f;
  #pragma unroll
  for (int q = 0; q < 8; ++q) {
    float f[8]; ld8(row + 8 * q, f);
    float4 va = *(const float4*)&vec[8 * q];
    float4 vb = *(const float4*)&vec[8 * q + 4];
    a0 = fmaf(va.x, f[0], a0); a1 = fmaf(va.y, f[1], a1);
    a2 = fmaf(va.z, f[2], a2); a3 = fmaf(va.w, f[3], a3);
    a0 = fmaf(vb.x, f[4], a0); a1 = fmaf(vb.y, f[5], a1);
    a2 = fmaf(vb.z, f[6], a2); a3 = fmaf(vb.w, f[7], a3);
  }
  return (a0 + a1) + (a2 + a3);
}

struct alignas(16) Smem {
  // M rows 512..1023: [block b=col/4][row r][4 floats]; lane-contiguous b128.
  float M1s[16 * 512 * 4];   // 128 KB
  float partA[1280];         // [0..268) head dots | [512..576) outc dots
                             // | [768..1280) butterfly wave partials
  float E[kN];               // unnormalized content softmax numerators
  float WP[kN];              // previous weights (for shift conv)
  float c[kC];               // controller activations
  float r[kMV];              // read vector
  float k[kMV], kr[kMV], e[kMV], a[kMV];
  float bcS[kC], bwS[kHW], brS[kHR], bfS[kOUT];   // biases (staged once)
  float red[2][NW];          // cross-wave reduction slots
  float scal[16];            // 6: |k| write, 14: |k| read
};
static_assert(sizeof(Smem) <= 160 * 1024, "LDS budget");

__device__ __forceinline__ int m1idx(int blk, int row) { return (blk * 512 + row) * 4; }

// flag: 1 if buffers are bf16, 0 if fp32.  w_bias is a softmax -> sums to 1.
__global__ void detect_dtype(const void* wb, int* flag) {
  const unsigned short* u = (const unsigned short*)wb;
  int lane = threadIdx.x;
  float s = 0.f;
  for (int i = lane; i < kN; i += 64)
    s += __uint_as_float(((unsigned int)u[i]) << 16);
  s = wsum(s);
  if (lane == 0 && blockIdx.x == 0)
    *flag = (s > 0.75f && s < 1.25f) ? 1 : 0;
}

// Merged pre-pass: blocks 0..255 repack all hot weights to fp32; blocks
// 256.. run cpre (reads ORIGINAL Wc -> no dependency on the repack blocks;
// acc[i&3] summation order == rev 13's dot64 -> bit-identical results).
template <typename TD, int WANT>
__global__ void pre_kernel(const TD* __restrict__ Wc, const TD* __restrict__ Ww,
                           const TD* __restrict__ Wr, const TD* __restrict__ Wf,
                           const TD* __restrict__ x, const TD* __restrict__ bc,
                           float* __restrict__ pk, float* __restrict__ cpre,
                           const int* __restrict__ flag) {
  if (*flag != WANT) return;
  if (blockIdx.x < 256) {
    for (int idx = blockIdx.x * blockDim.x + threadIdx.x; idx < kPTotal;
         idx += 256 * 256) {
      float v = 0.0f;
      if (idx < kPHc) {                        // WcT[j][i] = Wc[i][j]
        int r = idx, j = r >> 7, i = r & 127;
        v = ldf(Wc, i * kC + j);
      } else if (idx < kPWfT) {                // HeadCat[i][o] = Ww[i][o] || Wr
        int r = idx - kPHc, i = r / kHCP, o = r - i * kHCP;
        if (o < kHW) v = ldf(Ww, i * kHW + o);
        else if (o < kHO) v = ldf(Wr, i * kHR + (o - kHW));
      } else if (idx < kPWcR) {                // WfT[j][i] = Wf[i][j]
        int r = idx - kPWfT, j = r / 320, i = r % 320;
        v = ldf(Wf, i * kOUT + j);
      } else if (idx < kPWfR) {                // WcR[i][j] = Wc[64+i][j]
        int r = idx - kPWcR, i = r >> 8, j = r & 255;
        v = ldf(Wc, (kIN + i) * kC + j);
      } else {                                 // WfR[i][j] = Wf[i][j]
        int r = idx - kPWfR, i = r >> 6, j = r & 63;
        v = ldf(Wf, i * kOUT + j);
      }
      pk[idx] = v;
    }
  } else {
    // cpre[bt][j] = bc[j] + sum_{i<64} x[bt][i] * Wc[i][j]
    const int bt = blockIdx.x - 256;          // 0..B*T-1
    const int tid = threadIdx.x;              // output j (0..255)
    __shared__ float xs[kIN];
    if (tid < kIN) xs[tid] = ldf(x, (size_t)bt * kIN + tid);
    __syncthreads();
    float a0 = 0.f, a1 = 0.f, a2 = 0.f, a3 = 0.f;
    #pragma unroll
    for (int i = 0; i < kIN; i += 4) {        // coalesced over j per i
      a0 = fmaf(xs[i],     ldf(Wc, (i)     * kC + tid), a0);
      a1 = fmaf(xs[i + 1], ldf(Wc, (i + 1) * kC + tid), a1);
      a2 = fmaf(xs[i + 2], ldf(Wc, (i + 2) * kC + tid), a2);
      a3 = fmaf(xs[i + 3], ldf(Wc, (i + 3) * kC + tid), a3);
    }
    cpre[(size_t)bt * kC + tid] = ldf(bc, tid) + ((a0 + a1) + (a2 + a3));
  }
}

// MODE: 2 = packed + cpre, 1 = packed (x-part inline), 0 = direct strided.
template <typename TD, int WANT, int MODE>
__global__ __launch_bounds__(NT, 1) void ntm_fused(
    const TD* __restrict__ x,
    const TD* __restrict__ Wc, const TD* __restrict__ bc,
    const TD* __restrict__ Wr, const TD* __restrict__ br,
    const TD* __restrict__ Ww, const TD* __restrict__ bw,
    const TD* __restrict__ Wf, const TD* __restrict__ bf,
    const TD* __restrict__ r_bias, const TD* __restrict__ w_bias,
    const TD* __restrict__ M_bias,
    const float* __restrict__ pk, const float* __restrict__ cpre,
    TD* __restrict__ out, const int* __restrict__ flag) {
  if (*flag != WANT) return;
  __shared__ Smem sm;
  const int tid  = threadIdx.x;
  const int b    = blockIdx.x;
  const int lane = tid & 63;
  const int wid  = tid >> 6;

  // ---- one-time staging: biases, r_bias
  if (tid < kC)  sm.bcS[tid] = ldf(bc, tid);
  if (tid < kHW) sm.bwS[tid] = ldf(bw, tid);
  if (tid < kHR) sm.brS[tid] = ldf(br, tid);
  if (tid < kOUT) sm.bfS[tid] = ldf(bf, tid);
  if (tid < kMV) sm.r[tid] = ldf(r_bias, tid);

  // ---- init state: reg row (tid) + LDS row (tid+512), norms, prev weights
  float M0[kMV];
  float n2_0 = 0.f, n2_1 = 0.f;
  #pragma unroll
  for (int jb = 0; jb < kMV; jb += 8) {
    float f0[8], f1[8];
    ld8(M_bias + (size_t)tid * kMV + jb, f0);
    ld8(M_bias + (size_t)(tid + NT) * kMV + jb, f1);
    #pragma unroll
    for (int u = 0; u < 8; ++u) {
      M0[jb + u] = f0[u];
      n2_0 = fmaf(f0[u], f0[u], n2_0);
      n2_1 = fmaf(f1[u], f1[u], n2_1);
    }
    *(float4*)&sm.M1s[m1idx(jb >> 2, tid)] = make_float4(f1[0], f1[1], f1[2], f1[3]);
    *(float4*)&sm.M1s[m1idx((jb >> 2) + 1, tid)] = make_float4(f1[4], f1[5], f1[6], f1[7]);
  }
  float wp0 = ldf(w_bias, tid);
  float wp1 = ldf(w_bias, tid + NT);
  __syncthreads();

  #pragma unroll 1
  for (int t = 0; t < kT; ++t) {
    // ==== SEG 1: controller (coalesced si-split, waves 0..3)  ||  out store
    //     for step t-1 (threads 256..319).  Both depend only on r_{t-1}.
    if constexpr (MODE == 2) {
      if (tid < 256) {
        const int si = lane >> 3;                 // i-slice 0..7
        const int g  = (wid << 3) + (lane & 7);   // output group 0..31
        const int obase = g * 8;
        float acc[8] = {0.f, 0.f, 0.f, 0.f, 0.f, 0.f, 0.f, 0.f};
        #pragma unroll
        for (int q = 0; q < 8; ++q) {
          int i = (q << 3) + si;
          float rv = sm.r[i];
          float f[8]; ld8(pk + kPWcR + i * kC + obase, f);   // fp32 WcR row
          #pragma unroll
          for (int v = 0; v < 8; ++v) acc[v] = fmaf(rv, f[v], acc[v]);
        }
        #pragma unroll
        for (int v = 0; v < 8; ++v) {
          acc[v] += __shfl_xor(acc[v], 8);
          acc[v] += __shfl_xor(acc[v], 16);
          acc[v] += __shfl_xor(acc[v], 32);
        }
        if (si == 0) {
          const float* cp = &cpre[((size_t)b * kT + t) * kC + obase];
          float4 ca = *(const float4*)cp;
          float4 cb = *(const float4*)(cp + 4);
          sm.c[obase + 0] = ftanh(ca.x + acc[0]);
          sm.c[obase + 1] = ftanh(ca.y + acc[1]);
          sm.c[obase + 2] = ftanh(ca.z + acc[2]);
          sm.c[obase + 3] = ftanh(ca.w + acc[3]);
          sm.c[obase + 4] = ftanh(cb.x + acc[4]);
          sm.c[obase + 5] = ftanh(cb.y + acc[5]);
          sm.c[obase + 6] = ftanh(cb.z + acc[6]);
          sm.c[obase + 7] = ftanh(cb.w + acc[7]);
        }
      } else if (tid < 320 && t > 0) {
        const int j = tid - 256;
        float s = sm.bfS[j] + sm.partA[512 + j];
        s += dot64(pk + kPWfT + j * (kC + kMV) + kC, sm.r);
        stf(out, ((size_t)b * kT + (t - 1)) * kOUT + j, sigmoidf_(s));
      }
    } else {
      if (tid < kC) {
        float s;
        if constexpr (MODE == 1) {
          s = sm.bcS[tid];
          const TD* xrow = x + ((size_t)b * kT + t) * kIN;
          const float* row = pk + kPWcT + tid * 128;
          #pragma unroll
          for (int q = 0; q < 8; ++q) {
            float f[8], xv[8];
            ld8(row + 8 * q, f); ld8(xrow + 8 * q, xv);
            #pragma unroll
            for (int u = 0; u < 8; ++u) s = fmaf(xv[u], f[u], s);
          }
          s += dot64(pk + kPWcT + tid * 128 + 64, sm.r);
        } else {
          s = sm.bcS[tid];
          for (int i = 0; i < kIN; ++i)
            s = fmaf(ldf(x, ((size_t)b * kT + t) * kIN + i), ldf(Wc, i * kC + tid), s);
          for (int i = 0; i < kMV; ++i)
            s = fmaf(sm.r[i], ldf(Wc, (kIN + i) * kC + tid), s);
        }
        sm.c[tid] = ftanh(s);
      } else if (tid < 320 && t > 0) {
        const int j = tid - 256;
        float s = sm.bfS[j] + sm.partA[512 + j];
        if constexpr (MODE == 1) {
          s += dot64(pk + kPWfT + j * (kC + kMV) + kC, sm.r);
        } else {
          for (int i = 0; i < kMV; ++i)
            s = fmaf(sm.r[i], ldf(Wf, (kC + i) * kOUT + j), s);
        }
        stf(out, ((size_t)b * kT + (t - 1)) * kOUT + j, sigmoidf_(s));
      }
    }
    __syncthreads();                                               // B1

    // ==== SEG 2: head full-dots (si-split over HeadCat, waves 0..4)
    //     || outc full-dots (wave 5, si-split over WfR) || waves 6-7 idle
    if constexpr (MODE >= 1) {
      if (wid < 5) {
        const int si = lane >> 3;                 // i-slice 0..7
        const int g  = (wid << 3) + (lane & 7);   // output group 0..39
        const int obase = g * 8;                  // 0..312 (padded rows safe)
        float acc[8] = {0.f, 0.f, 0.f, 0.f, 0.f, 0.f, 0.f, 0.f};
        #pragma unroll 4
        for (int q = 0; q < 32; ++q) {
          int i = (q << 3) + si;
          float cv = sm.c[i];
          float f[8]; ld8(pk + kPHc + i * kHCP + obase, f);
          #pragma unroll
          for (int v = 0; v < 8; ++v) acc[v] = fmaf(cv, f[v], acc[v]);
        }
        #pragma unroll
        for (int v = 0; v < 8; ++v) {
          acc[v] += __shfl_xor(acc[v], 8);
          acc[v] += __shfl_xor(acc[v], 16);
          acc[v] += __shfl_xor(acc[v], 32);
        }
        if (si == 0 && obase < kHO) {
          #pragma unroll
          for (int v = 0; v < 8; ++v)
            if (obase + v < kHO) sm.partA[obase + v] = acc[v];
        }
      } else if (wid == 5) {
        const int si = lane >> 3;
        const int g  = lane & 7;                  // output group 0..7
        const int obase = g * 8;
        float acc[8] = {0.f, 0.f, 0.f, 0.f, 0.f, 0.f, 0.f, 0.f};
        #pragma unroll 4
        for (int q = 0; q < 32; ++q) {
          int i = (q << 3) + si;
          float cv = sm.c[i];
          float f[8]; ld8(pk + kPWfR + i * kOUT + obase, f);
          #pragma unroll
          for (int v = 0; v < 8; ++v) acc[v] = fmaf(cv, f[v], acc[v]);
        }
        #pragma unroll
        for (int v = 0; v < 8; ++v) {
          acc[v] += __shfl_xor(acc[v], 8);
          acc[v] += __shfl_xor(acc[v], 16);
          acc[v] += __shfl_xor(acc[v], 32);
        }
        if (si == 0) {
          *(float4*)&sm.partA[512 + obase] =
              make_float4(acc[0], acc[1], acc[2], acc[3]);
          *(float4*)&sm.partA[512 + obase + 4] =
              make_float4(acc[4], acc[5], acc[6], acc[7]);
        }
      }
    } else {
      if (tid < kHO) {
        float a0 = 0.f;
        for (int i = 0; i < kC; ++i) {
          float wv = (tid < kHW) ? ldf(Ww, i * kHW + tid)
                                 : ldf(Wr, i * kHR + (tid - kHW));
          a0 = fmaf(sm.c[i], wv, a0);
        }
        sm.partA[tid] = a0;
      } else if (wid == 5) {                // outc (strided fallback)
        const int si = lane >> 3;
        const int g  = lane & 7;
        const int obase = g * 8;
        float acc[8] = {0.f, 0.f, 0.f, 0.f, 0.f, 0.f, 0.f, 0.f};
        for (int q = 0; q < 32; ++q) {
          int i = (q << 3) + si;
          float cv = sm.c[i];
          #pragma unroll
          for (int v = 0; v < 8; ++v)
            acc[v] = fmaf(cv, ldf(Wf, i * kOUT + obase + v), acc[v]);
        }
        #pragma unroll
        for (int v = 0; v < 8; ++v) {
          acc[v] += __shfl_xor(acc[v], 8);
          acc[v] += __shfl_xor(acc[v], 16);
          acc[v] += __shfl_xor(acc[v], 32);
        }
        if (si == 0) {
          #pragma unroll
          for (int v = 0; v < 8; ++v) sm.partA[512 + obase + v] = acc[v];
        }
      }
    }
    __syncthreads();                                               // B2

    // ==== SEG 3: head vector params only (waves 0..3; short pole)
    if (wid == 0) {                       // write key + |k|
      float kv = ftanh(sm.partA[lane] + sm.bwS[lane]);
      sm.k[lane] = kv;
      float s = wsum(kv * kv);
      if (lane == 0) sm.scal[6] = sqrtf(s);
    } else if (wid == 1) {                // erase
      sm.e[lane] = sigmoidf_(sm.partA[70 + lane] + sm.bwS[70 + lane]);
    } else if (wid == 2) {                // add
      sm.a[lane] = ftanh(sm.partA[134 + lane] + sm.bwS[134 + lane]);
    } else if (wid == 3) {                // read key + |k|
      float kv = ftanh(sm.partA[kHW + lane] + sm.brS[lane]);
      sm.kr[lane] = kv;
      float s = wsum(kv * kv);
      if (lane == 0) sm.scal[14] = sqrtf(s);
    }
    __syncthreads();                                               // B3

    // ==== SEG 4: write-head addressing, part 1 (dots + exp + block sum)
    float ww0, ww1, gW, s0W, s1W, s2W, gammaW;
    float e0W, e1W, p0W, p1W;
    {
      float beta = softplusf_(sm.partA[64] + sm.bwS[64]);
      gW = sigmoidf_(sm.partA[65] + sm.bwS[65]);
      gammaW = 1.f + softplusf_(sm.partA[69] + sm.bwS[69]);
      float a0 = sm.partA[66] + sm.bwS[66];
      float a1 = sm.partA[67] + sm.bwS[67];
      float a2 = sm.partA[68] + sm.bwS[68];
      float mx = fmaxf(a0, fmaxf(a1, a2));
      float ex0 = fexp(a0 - mx), ex1 = fexp(a1 - mx), ex2 = fexp(a2 - mx);
      float dd = __fdividef(1.f, ex0 + ex1 + ex2);
      s0W = ex0 * dd; s1W = ex1 * dd; s2W = ex2 * dd;
      float kn = sm.scal[6];
      float d0a = 0.f, d0b = 0.f, d1a = 0.f, d1b = 0.f;
      #pragma unroll
      for (int bq = 0; bq < 16; ++bq) {
        float4 kv = *(const float4*)&sm.k[bq * 4];
        d0a = fmaf(M0[bq * 4],     kv.x, d0a);
        d0b = fmaf(M0[bq * 4 + 1], kv.y, d0b);
        d0a = fmaf(M0[bq * 4 + 2], kv.z, d0a);
        d0b = fmaf(M0[bq * 4 + 3], kv.w, d0b);
        float4 mv = *(const float4*)&sm.M1s[m1idx(bq, tid)];
        d1a = fmaf(mv.x, kv.x, d1a); d1b = fmaf(mv.y, kv.y, d1b);
        d1a = fmaf(mv.z, kv.z, d1a); d1b = fmaf(mv.w, kv.w, d1b);
      }
      float d0 = d0a + d0b, d1 = d1a + d1b;
      float sim0 = fminf(beta * d0 / (sqrtf(n2_0) * kn + kEPS), 80.f);
      float sim1 = fminf(beta * d1 / (sqrtf(n2_1) * kn + kEPS), 80.f);
      e0W = fexp(sim0); e1W = fexp(sim1);
      sm.E[tid] = e0W; sm.E[tid + NT] = e1W;
      sm.WP[tid] = wp0; sm.WP[tid + NT] = wp1;
      float sv = wsum(e0W + e1W);
      if (lane == 0) sm.red[0][wid] = sv;
    }
    __syncthreads();                                               // B4

    // ==== SEG 5: write-head addressing, part 2 (norm + shift + sharpen)
    {
      float gsum = 0.f;
      #pragma unroll
      for (int i = 0; i < NW; ++i) gsum += sm.red[0][i];
      float inv = __fdividef(1.f, gsum);
      float wg0 = fmaf(gW, fmaf(e0W, inv, -wp0), wp0);
      float wg1 = fmaf(gW, fmaf(e1W, inv, -wp1), wp1);
      int np = (tid + 1) & (kN - 1), nm = (tid + kN - 1) & (kN - 1);
      float wgp = fmaf(gW, fmaf(sm.E[np], inv, -sm.WP[np]), sm.WP[np]);
      float wgm = fmaf(gW, fmaf(sm.E[nm], inv, -sm.WP[nm]), sm.WP[nm]);
      float ws0 = s0W * wgp + s1W * wg0 + s2W * wgm;
      int npb = (tid + NT + 1) & (kN - 1), nmb = (tid + NT - 1) & (kN - 1);
      float wgpb = fmaf(gW, fmaf(sm.E[npb], inv, -sm.WP[npb]), sm.WP[npb]);
      float wgmb = fmaf(gW, fmaf(sm.E[nmb], inv, -sm.WP[nmb]), sm.WP[nmb]);
      float ws1 = s0W * wgpb + s1W * wg1 + s2W * wgmb;
      p0W = fexp(gammaW * __logf(ws0 + kEPS));
      p1W = fexp(gammaW * __logf(ws1 + kEPS));
      float pv = wsum(p0W + p1W);
      if (lane == 0) sm.red[1][wid] = pv;
    }
    __syncthreads();                                               // B5
    {
      float psum = 0.f;
      #pragma unroll
      for (int i = 0; i < NW; ++i) psum += sm.red[1][i];
      float ipn = __fdividef(1.f, psum);
      ww0 = p0W * ipn; ww1 = p1W * ipn;
    }

    // ==== SEG 6: memory update (+ read dot + norms) + read-head part 1
    float gR, s0R, s1R, s2R, gammaR;
    float e0R, e1R, p0R, p1R;
    float dr0 = 0.f, dr1 = 0.f, nn0 = 0.f, nn1 = 0.f;
    {
      #pragma unroll
      for (int bq = 0; bq < 16; ++bq) {
        float4 ev = *(const float4*)&sm.e[bq * 4];
        float4 av = *(const float4*)&sm.a[bq * 4];
        float4 kv = *(const float4*)&sm.kr[bq * 4];
        {
          float m = fmaf(ww0, fmaf(-ev.x, M0[bq * 4], av.x), M0[bq * 4]);
          M0[bq * 4] = m; dr0 = fmaf(m, kv.x, dr0); nn0 = fmaf(m, m, nn0);
        }
        {
          float m = fmaf(ww0, fmaf(-ev.y, M0[bq * 4 + 1], av.y), M0[bq * 4 + 1]);
          M0[bq * 4 + 1] = m; dr0 = fmaf(m, kv.y, dr0); nn0 = fmaf(m, m, nn0);
        }
        {
          float m = fmaf(ww0, fmaf(-ev.z, M0[bq * 4 + 2], av.z), M0[bq * 4 + 2]);
          M0[bq * 4 + 2] = m; dr0 = fmaf(m, kv.z, dr0); nn0 = fmaf(m, m, nn0);
        }
        {
          float m = fmaf(ww0, fmaf(-ev.w, M0[bq * 4 + 3], av.w), M0[bq * 4 + 3]);
          M0[bq * 4 + 3] = m; dr0 = fmaf(m, kv.w, dr0); nn0 = fmaf(m, m, nn0);
        }
        int fi = m1idx(bq, tid);
        float4 mv = *(const float4*)&sm.M1s[fi];
        float4 nm;
        nm.x = fmaf(ww1, fmaf(-ev.x, mv.x, av.x), mv.x);
        dr1 = fmaf(nm.x, kv.x, dr1); nn1 = fmaf(nm.x, nm.x, nn1);
        nm.y = fmaf(ww1, fmaf(-ev.y, mv.y, av.y), mv.y);
        dr1 = fmaf(nm.y, kv.y, dr1); nn1 = fmaf(nm.y, nm.y, nn1);
        nm.z = fmaf(ww1, fmaf(-ev.z, mv.z, av.z), mv.z);
        dr1 = fmaf(nm.z, kv.z, dr1); nn1 = fmaf(nm.z, nm.z, nn1);
        nm.w = fmaf(ww1, fmaf(-ev.w, mv.w, av.w), mv.w);
        dr1 = fmaf(nm.w, kv.w, dr1); nn1 = fmaf(nm.w, nm.w, nn1);
        *(float4*)&sm.M1s[fi] = nm;
      }
      float beta = softplusf_(sm.partA[kHW + 64] + sm.brS[64]);
      gR = sigmoidf_(sm.partA[kHW + 65] + sm.brS[65]);
      gammaR = 1.f + softplusf_(sm.partA[kHW + 69] + sm.brS[69]);
      float a0 = sm.partA[kHW + 66] + sm.brS[66];
      float a1 = sm.partA[kHW + 67] + sm.brS[67];
      float a2 = sm.partA[kHW + 68] + sm.brS[68];
      float mx = fmaxf(a0, fmaxf(a1, a2));
      float ex0 = fexp(a0 - mx), ex1 = fexp(a1 - mx), ex2 = fexp(a2 - mx);
      float dd = __fdividef(1.f, ex0 + ex1 + ex2);
      s0R = ex0 * dd; s1R = ex1 * dd; s2R = ex2 * dd;
      float kn = sm.scal[14];
      float sim0 = fminf(beta * dr0 / (sqrtf(nn0) * kn + kEPS), 80.f);
      float sim1 = fminf(beta * dr1 / (sqrtf(nn1) * kn + kEPS), 80.f);
      e0R = fexp(sim0); e1R = fexp(sim1);
      sm.E[tid] = e0R; sm.E[tid + NT] = e1R;
      sm.WP[tid] = ww0; sm.WP[tid + NT] = ww1;
      float sv = wsum(e0R + e1R);
      if (lane == 0) sm.red[0][wid] = sv;
    }
    __syncthreads();                                               // B6

    // ==== SEG 7: read-head part 2 + butterfly on UNNORMALIZED p
    {
      float gsum = 0.f;
      #pragma unroll
      for (int i = 0; i < NW; ++i) gsum += sm.red[0][i];
      float inv = __fdividef(1.f, gsum);
      float wg0 = fmaf(gR, fmaf(e0R, inv, -ww0), ww0);
      float wg1 = fmaf(gR, fmaf(e1R, inv, -ww1), ww1);
      int np = (tid + 1) & (kN - 1), nm = (tid + kN - 1) & (kN - 1);
      float wgp = fmaf(gR, fmaf(sm.E[np], inv, -sm.WP[np]), sm.WP[np]);
      float wgm = fmaf(gR, fmaf(sm.E[nm], inv, -sm.WP[nm]), sm.WP[nm]);
      float ws0 = s0R * wgp + s1R * wg0 + s2R * wgm;
      int npb = (tid + NT + 1) & (kN - 1), nmb = (tid + NT - 1) & (kN - 1);
      float wgpb = fmaf(gR, fmaf(sm.E[npb], inv, -sm.WP[npb]), sm.WP[npb]);
      float wgmb = fmaf(gR, fmaf(sm.E[nmb], inv, -sm.WP[nmb]), sm.WP[nmb]);
      float ws1 = s0R * wgpb + s1R * wg1 + s2R * wgmb;
      p0R = fexp(gammaR * __logf(ws0 + kEPS));
      p1R = fexp(gammaR * __logf(ws1 + kEPS));
      float pv = wsum(p0R + p1R);
      if (lane == 0) sm.red[1][wid] = pv;
      // butterfly pass A: columns 0..31, weights p0R/p1R (unnormalized)
      {
        float cur[16];
        const int b0 = lane & 1;
        #pragma unroll
        for (int qq = 0; qq < 8; ++qq) {
          float4 mv = *(const float4*)&sm.M1s[m1idx(qq, tid)];
          float v0 = fmaf(p0R, M0[4 * qq],     p1R * mv.x);
          float v1 = fmaf(p0R, M0[4 * qq + 1], p1R * mv.y);
          float keep = b0 ? v1 : v0, send = b0 ? v0 : v1;
          cur[2 * qq] = keep + __shfl_xor(send, 1);
          float v2 = fmaf(p0R, M0[4 * qq + 2], p1R * mv.z);
          float v3 = fmaf(p0R, M0[4 * qq + 3], p1R * mv.w);
          keep = b0 ? v3 : v2; send = b0 ? v2 : v3;
          cur[2 * qq + 1] = keep + __shfl_xor(send, 1);
        }
        #pragma unroll
        for (int st = 1; st < 5; ++st) {
          const int d = 1 << st;
          const int bb = (lane >> st) & 1;
          #pragma unroll
          for (int q = 0; q < (16 >> st); ++q) {
            float x0 = cur[2 * q], x1 = cur[2 * q + 1];
            float keep = bb ? x1 : x0, send = bb ? x0 : x1;
            cur[q] = keep + __shfl_xor(send, d);
          }
        }
        float tot = cur[0] + __shfl_xor(cur[0], 32);
        if (lane < 32) sm.partA[768 + wid * 64 + lane] = tot;
      }
      // butterfly pass B: columns 32..63
      {
        float cur[16];
        const int b0 = lane & 1;
        #pragma unroll
        for (int qq = 0; qq < 8; ++qq) {
          float4 mv = *(const float4*)&sm.M1s[m1idx(8 + qq, tid)];
          float v0 = fmaf(p0R, M0[32 + 4 * qq],     p1R * mv.x);
          float v1 = fmaf(p0R, M0[32 + 4 * qq + 1], p1R * mv.y);
          float keep = b0 ? v1 : v0, send = b0 ? v0 : v1;
          cur[2 * qq] = keep + __shfl_xor(send, 1);
          float v2 = fmaf(p0R, M0[32 + 4 * qq + 2], p1R * mv.z);
          float v3 = fmaf(p0R, M0[32 + 4 * qq + 3], p1R * mv.w);
          keep = b0 ? v3 : v2; send = b0 ? v2 : v3;
          cur[2 * qq + 1] = keep + __shfl_xor(send, 1);
        }
        #pragma unroll
        for (int st = 1; st < 5; ++st) {
          const int d = 1 << st;
          const int bb = (lane >> st) & 1;
          #pragma unroll
          for (int q = 0; q < (16 >> st); ++q) {
            float x0 = cur[2 * q], x1 = cur[2 * q + 1];
            float keep = bb ? x1 : x0, send = bb ? x0 : x1;
            cur[q] = keep + __shfl_xor(send, d);
          }
        }
        float tot = cur[0] + __shfl_xor(cur[0], 32);
        if (lane < 32) sm.partA[768 + wid * 64 + 32 + lane] = tot;
      }
    }
    __syncthreads();                                               // B7

    // ==== SEG 8: psum -> ipn; carry state; r reduce with ipn scaling
    {
      float psum = 0.f;
      #pragma unroll
      for (int i = 0; i < NW; ++i) psum += sm.red[1][i];
      float ipn = __fdividef(1.f, psum);
      wp0 = p0R * ipn; wp1 = p1R * ipn;      // carry normalized read weights
      n2_0 = nn0; n2_1 = nn1;
      if (tid < kMV) {
        float s = sm.partA[768 + tid];
        #pragma unroll
        for (int w = 1; w < NW; ++w) s += sm.partA[768 + w * 64 + tid];
        sm.r[tid] = s * ipn;
      }
    }
    __syncthreads();                                               // B8
  }

  // ==== epilogue: output for t = kT-1 (outc dots + r are intact)
  if (tid >= 256 && tid < 320) {
    const int j = tid - 256;
    float s = sm.bfS[j] + sm.partA[512 + j];
    if constexpr (MODE >= 1) {
      s += dot64(pk + kPWfT + j * (kC + kMV) + kC, sm.r);
    } else {
      for (int i = 0; i < kMV; ++i)
        s = fmaf(sm.r[i], ldf(Wf, (kC + i) * kOUT + j), s);
    }
    stf(out, ((size_t)b * kT + (kT - 1)) * kOUT + j, sigmoidf_(s));
  }
}

template <typename TD, int WANT, int MODE>
static void launch_variant(void* const* d_in, void* d_out, const int* flag,
                           const float* pk, const float* cpre, hipStream_t stream) {
  ntm_fused<TD, WANT, MODE><<<dim3(kB), dim3(NT), 0, stream>>>(
      (const TD*)d_in[0], (const TD*)d_in[1], (const TD*)d_in[2],
      (const TD*)d_in[3], (const TD*)d_in[4], (const TD*)d_in[5],
      (const TD*)d_in[6], (const TD*)d_in[7], (const TD*)d_in[8],
      (const TD*)d_in[9], (const TD*)d_in[10], (const TD*)d_in[11],
      pk, cpre, (TD*)d_out, flag);
}

template <typename TD, int WANT>
static void launch_pre(void* const* d_in, float* pk, float* cpre, int nblk,
                       const int* flag, hipStream_t stream) {
  pre_kernel<TD, WANT><<<dim3(nblk), dim3(256), 0, stream>>>(
      (const TD*)d_in[1], (const TD*)d_in[5], (const TD*)d_in[3],
      (const TD*)d_in[7], (const TD*)d_in[0], (const TD*)d_in[2],
      pk, cpre, flag);
}

extern "C" void kernel_launch(void* const* d_in, const int* in_sizes, int n_in,
                              void* d_out, int out_size, void* d_ws, size_t ws_size,
                              hipStream_t stream) {
  (void)in_sizes; (void)n_in; (void)out_size;
  int* flag = (int*)d_ws;
  detect_dtype<<<dim3(1), dim3(64), 0, stream>>>(d_in[10], flag);
  if (ws_size >= kWsPack) {
    float* pk = (float*)((char*)d_ws + 256);
    if (ws_size >= kWsFull) {
      float* cpre = (float*)((char*)d_ws + kWsPack);
      launch_pre<__hip_bfloat16, 1>(d_in, pk, cpre, 256 + kB * kT, flag, stream);
      launch_pre<float, 0>(d_in, pk, cpre, 256 + kB * kT, flag, stream);
      launch_variant<__hip_bfloat16, 1, 2>(d_in, d_out, flag, pk, cpre, stream);
      launch_variant<float, 0, 2>(d_in, d_out, flag, pk, cpre, stream);
    } else {
      launch_pre<__hip_bfloat16, 1>(d_in, pk, nullptr, 256, flag, stream);
      launch_pre<float, 0>(d_in, pk, nullptr, 256, flag, stream);
      launch_variant<__hip_bfloat16, 1, 1>(d_in, d_out, flag, pk, nullptr, stream);
      launch_variant<float, 0, 1>(d_in, d_out, flag, pk, nullptr, stream);
    }
  } else {
    launch_variant<__hip_bfloat16, 1, 0>(d_in, d_out, flag, nullptr, nullptr, stream);
    launch_variant<float, 0, 0>(d_in, d_out, flag, nullptr, nullptr, stream);
  }
}